// Round 4
// baseline (274.654 us; speedup 1.0000x reference)
//
#include <hip/hip_runtime.h>

#define B_SZ 1024
#define DIN 512
#define HH 512   // H
#define DOUT 512

// ---------------------------------------------------------------------------
// prep: wb[i][j] = (j>i) ? {W_hh[i][j], b_hh[i][j]} : {0, -1}, padded to
// 512 rows (row 511 fully masked). relu(0*h - 1) = 0 -> masked entries
// contribute nothing, so the scan hot loops need no masking.
// ---------------------------------------------------------------------------
__global__ __launch_bounds__(256)
void prep_kernel(const float* __restrict__ W_hh,
                 const float* __restrict__ b_hh,
                 float2* __restrict__ wb) {
    int idx = blockIdx.x * 256 + threadIdx.x;   // over 512*512, exact grid
    int i = idx >> 9;          // 0..511
    int j = idx & 511;
    float2 o;
    if (j > i) { o.x = W_hh[idx]; o.y = b_hh[idx]; }  // i<=510 whenever j>i
    else       { o.x = 0.0f;      o.y = -1.0f;     }
    wb[idx] = o;
}

// ---------------------------------------------------------------------------
// fp32 GEMM: C = act(A[M,K] @ B[K,N] + bias). BM=64, BN=32, BK=32,
// 256 threads, 4x2 microtile. LDS layouts: As[k][m] stride 66, Bs[k][n]
// stride 36 -> all LDS reads are broadcasts / <=2-way conflicts (the
// round-2/3 layout read A along K and hit 8-way conflicts).
// Register-relay prefetch of the next K-tile pinned with sched_barrier.
// Grid (M/64, N/32) = 256 blocks -> 1 block/CU, 4 waves/CU.
// ---------------------------------------------------------------------------
template <bool ACT>
__global__ __launch_bounds__(256)
void gemm_kernel(const float* __restrict__ A,
                 const float* __restrict__ Bm,
                 const float* __restrict__ bias,
                 float* __restrict__ C,
                 int M, int N, int K) {
    __shared__ float As[32][66];   // [k][m]; stride 66: writes 2-way, reads bcast
    __shared__ float Bs[32][36];   // [k][n]; stride 36: writes 2-way, reads 2-way

    const int tid = threadIdx.x;
    const int bm = blockIdx.x * 64;
    const int bn = blockIdx.y * 32;
    const int ty = tid >> 4;        // 0..15 -> rows 4ty..4ty+3
    const int tx = tid & 15;        // cols 2tx..2tx+1
    const int ar = tid >> 2;        // A stage row 0..63
    const int ak = (tid & 3) * 8;   // A stage k 0,8,16,24
    const int bk = tid >> 3;        // B stage k 0..31
    const int bc = (tid & 7) * 4;   // B stage col 0..28

    float4 a0, a1, b0;              // relay registers
    auto stage = [&](int kt) {
        a0 = *(const float4*)&A[(size_t)(bm + ar) * K + kt + ak];
        a1 = *(const float4*)&A[(size_t)(bm + ar) * K + kt + ak + 4];
        b0 = *(const float4*)&Bm[(size_t)(kt + bk) * N + bn + bc];
    };

    float acc[4][2] = {};

    stage(0);
    for (int kt = 0; kt < K; kt += 32) {
        __syncthreads();
        #pragma unroll
        for (int u = 0; u < 4; ++u) {
            As[ak + u][ar]     = ((const float*)&a0)[u];
            As[ak + 4 + u][ar] = ((const float*)&a1)[u];
        }
        *(float4*)&Bs[bk][bc] = b0;
        __syncthreads();
        if (kt + 32 < K) stage(kt + 32);
        __builtin_amdgcn_sched_barrier(0);

        #pragma unroll
        for (int k = 0; k < 32; ++k) {
            const float2 aA = *(const float2*)&As[k][4 * ty];
            const float2 aB = *(const float2*)&As[k][4 * ty + 2];
            const float2 bf = *(const float2*)&Bs[k][2 * tx];
            acc[0][0] = fmaf(aA.x, bf.x, acc[0][0]);
            acc[0][1] = fmaf(aA.x, bf.y, acc[0][1]);
            acc[1][0] = fmaf(aA.y, bf.x, acc[1][0]);
            acc[1][1] = fmaf(aA.y, bf.y, acc[1][1]);
            acc[2][0] = fmaf(aB.x, bf.x, acc[2][0]);
            acc[2][1] = fmaf(aB.x, bf.y, acc[2][1]);
            acc[3][0] = fmaf(aB.y, bf.x, acc[3][0]);
            acc[3][1] = fmaf(aB.y, bf.y, acc[3][1]);
        }
    }

    #pragma unroll
    for (int r = 0; r < 4; ++r) {
        const int row = bm + 4 * ty + r;
        const int col = bn + 2 * tx;
        float2 vv;
        vv.x = acc[r][0] + bias[col];
        vv.y = acc[r][1] + bias[col + 1];
        if (ACT) {
            vv.x = fmaxf(vv.x, 0.f); vv.x *= vv.x;
            vv.y = fmaxf(vv.y, 0.f); vv.y *= vv.y;
        }
        *(float2*)&C[(size_t)row * N + col] = vv;
    }
}

// ---------------------------------------------------------------------------
// Blocked triangular scan v4. 256 blocks x 512 threads (8 waves, 2/SIMD).
// Block owns 4 batch rows. Wave = (row-group rg of 2 rows, v=0..3) owns
// chunk pair {v, 7-v}: chunk j receives j rect tiles -> each wave gets
// exactly 7 tiles (perfect balance). Per chunk C:
//   - stage diag tile C+1 into LDS double buffer (overlaps diag C)
//   - diag: owner waves run 64 serial steps (2 rows interleaved), weights
//     from LDS via an 8-deep register ring; publish h-chunk to hpub
//   - barrier; rect: weights straight from L2-hot global (b64/lane),
//     8-step double-buffered register batches pinned with sched_barrier;
//     h values broadcast via readlane of one register.
// ---------------------------------------------------------------------------
__device__ __forceinline__ float rl(float x, int i) {
    return __uint_as_float(__builtin_amdgcn_readlane(__float_as_uint(x), i));
}

__global__ __launch_bounds__(512)
void scan_kernel(const float2* __restrict__ wb, float* __restrict__ h) {
    __shared__ float2 dbuf[2][4096];   // 2 x 32 KB diag tiles
    __shared__ float  hpub[8][4][64];  // 8 KB published h chunks

    const int tid  = threadIdx.x;
    const int lane = tid & 63;
    const int wave = tid >> 6;         // 0..7
    const int rg   = wave >> 2;        // row-group 0/1
    const int v    = wave & 3;         // 0..3
    const int r0   = blockIdx.x * 4 + rg * 2;
    const int cA = v, cB = 7 - v;      // owned chunks

    float hr[2][2];                    // [row in pair][0->cA, 1->cB]
    hr[0][0] = h[(size_t)r0 * HH + 64 * cA + lane];
    hr[0][1] = h[(size_t)r0 * HH + 64 * cB + lane];
    hr[1][0] = h[(size_t)(r0 + 1) * HH + 64 * cA + lane];
    hr[1][1] = h[(size_t)(r0 + 1) * HH + 64 * cB + lane];

    // stage diag tile 0 into dbuf[0] (rows 0..63 x cols 0..63)
    #pragma unroll
    for (int q = 0; q < 4; ++q) {
        const int e2 = 2 * (tid + 512 * q);
        const int rr2 = e2 >> 6, cc = e2 & 63;
        *(float4*)&dbuf[0][e2] = *(const float4*)&wb[(size_t)rr2 * HH + cc];
    }

    #pragma unroll 1
    for (int C = 0; C < 8; ++C) {
        __syncthreads();               // barrier1: dbuf[C&1] staged, rect C-1 done

        // stage diag tile C+1 (independent of diag C; overlaps it)
        if (C < 7) {
            const float2* src = wb + (size_t)(64 * (C + 1)) * HH + 64 * (C + 1);
            #pragma unroll
            for (int q = 0; q < 4; ++q) {
                const int e2 = 2 * (tid + 512 * q);
                const int rr2 = e2 >> 6, cc = e2 & 63;
                *(float4*)&dbuf[(C + 1) & 1][e2] =
                    *(const float4*)&src[(size_t)rr2 * HH + cc];
            }
        }

        // active rect tiles for this wave (j > C), cB first
        int jc[2], jx[2], nj = 0;
        if (cB > C) { jc[nj] = cB; jx[nj] = 1; ++nj; }
        if (cA > C) { jc[nj] = cA; jx[nj] = 0; ++nj; }

        const float2* b0 = wb + (size_t)(64 * C) * HH + lane;
        float2 wreg[2][8];
        if (nj > 0) {                  // prefetch first batch (overlaps diag)
            const float2* base = b0 + 64 * jc[0];
            #pragma unroll
            for (int u = 0; u < 8; ++u) wreg[0][u] = base[(size_t)u * HH];
        }

        // ---- diag: owner waves only
        const int dv = (C < 4) ? C : 7 - C;
        if (v == dv) {
            const int ci = (C == cA) ? 0 : 1;
            const float2* dt = dbuf[C & 1];
            float2 ring[8];
            #pragma unroll
            for (int u = 0; u < 8; ++u) ring[u] = dt[u * 64 + lane];
            #pragma unroll 1
            for (int i8 = 0; i8 < 8; ++i8) {
                #pragma unroll
                for (int u = 0; u < 8; ++u) {
                    const int i = i8 * 8 + u;
                    const float2 w = ring[u];
                    if (i8 < 7) ring[u] = dt[(i + 8) * 64 + lane];
                    #pragma unroll
                    for (int s = 0; s < 2; ++s) {
                        const float hi = rl(hr[s][ci], i);
                        float t = fmaf(hi, w.x, w.y);
                        t = fmaxf(t, 0.f);
                        hr[s][ci] = fmaf(t, t, hr[s][ci]);
                    }
                }
            }
            hpub[C][rg * 2 + 0][lane] = hr[0][ci];
            hpub[C][rg * 2 + 1][lane] = hr[1][ci];
        }
        __syncthreads();               // barrier2: hpub[C] ready
        if (nj == 0) continue;         // wave-coherent w.r.t. barrier counts

        float h64[2];
        h64[0] = hpub[C][rg * 2 + 0][lane];
        h64[1] = hpub[C][rg * 2 + 1][lane];

        // ---- rect: dependency-free accumulation, global weights (L2-hot)
        #pragma unroll 1
        for (int idx = 0; idx < nj; ++idx) {
            const int jj = jx[idx];
            const float2* base = b0 + 64 * jc[idx];
            if (idx > 0) {
                #pragma unroll
                for (int u = 0; u < 8; ++u) wreg[0][u] = base[(size_t)u * HH];
            }
            float a0 = hr[0][jj], a1 = hr[1][jj];
            #pragma unroll 1
            for (int t8 = 0; t8 < 8; ++t8) {
                if (t8 < 7) {
                    #pragma unroll
                    for (int u = 0; u < 8; ++u)
                        wreg[(t8 + 1) & 1][u] =
                            base[(size_t)((t8 + 1) * 8 + u) * HH];
                }
                __builtin_amdgcn_sched_barrier(0);  // keep loads above compute
                #pragma unroll
                for (int u = 0; u < 8; ++u) {
                    const int i = t8 * 8 + u;
                    const float2 w = wreg[t8 & 1][u];
                    float t0 = fmaf(rl(h64[0], i), w.x, w.y);
                    float t1 = fmaf(rl(h64[1], i), w.x, w.y);
                    t0 = fmaxf(t0, 0.f);
                    t1 = fmaxf(t1, 0.f);
                    a0 = fmaf(t0, t0, a0);
                    a1 = fmaf(t1, t1, a1);
                }
            }
            hr[0][jj] = a0; hr[1][jj] = a1;
        }
    }

    h[(size_t)r0 * HH + 64 * cA + lane]       = hr[0][0];
    h[(size_t)r0 * HH + 64 * cB + lane]       = hr[0][1];
    h[(size_t)(r0 + 1) * HH + 64 * cA + lane] = hr[1][0];
    h[(size_t)(r0 + 1) * HH + 64 * cB + lane] = hr[1][1];
}

// ---------------------------------------------------------------------------
extern "C" void kernel_launch(void* const* d_in, const int* in_sizes, int n_in,
                              void* d_out, int out_size, void* d_ws, size_t ws_size,
                              hipStream_t stream) {
    const float* x     = (const float*)d_in[0];
    const float* W_in  = (const float*)d_in[1];
    const float* b_in  = (const float*)d_in[2];
    const float* W_hh  = (const float*)d_in[3];
    const float* b_hh  = (const float*)d_in[4];
    const float* W_out = (const float*)d_in[5];
    const float* b_out = (const float*)d_in[6];
    float* out = (float*)d_out;

    // workspace: [0,2MB) wb (512x512 float2), [2MB,4MB) h (1024x512 f32)
    float2* wb = (float2*)d_ws;
    float*  h  = (float*)((char*)d_ws + (1u << 21));

    // 1) masked padded weights
    prep_kernel<<<dim3(1024), dim3(256), 0, stream>>>(W_hh, b_hh, wb);

    // 2) h0 = relu^2(x @ W_in + b_in)
    gemm_kernel<true><<<dim3(B_SZ / 64, HH / 32), dim3(256), 0, stream>>>(
        x, W_in, b_in, h, B_SZ, HH, DIN);

    // 3) blocked triangular scan, in-place on h
    scan_kernel<<<dim3(256), dim3(512), 0, stream>>>(wb, h);

    // 4) out = h @ W_out + b_out
    gemm_kernel<false><<<dim3(B_SZ / 64, DOUT / 32), dim3(256), 0, stream>>>(
        h, W_out, b_out, out, B_SZ, DOUT, HH);
}

// Round 5
// 217.709 us; speedup vs baseline: 1.2616x; 1.2616x over previous
//
#include <hip/hip_runtime.h>

#define B_SZ 1024
#define DIN 512
#define HH 512   // H
#define DOUT 512

__device__ __forceinline__ float rl(float x, int i) {
    return __uint_as_float(__builtin_amdgcn_readlane(__float_as_uint(x), i));
}

// ---------------------------------------------------------------------------
// prep: wb[i][j] = (j>i) ? {W_hh[i][j], b_hh[i][j]} : {0, -1}, padded to
// 512 rows (row 511 fully masked). relu(0*h - 1) = 0 -> masked entries
// contribute nothing, so the scan hot loops need no masking.
// ---------------------------------------------------------------------------
__global__ __launch_bounds__(256)
void prep_kernel(const float* __restrict__ W_hh,
                 const float* __restrict__ b_hh,
                 float2* __restrict__ wb) {
    int idx = blockIdx.x * 256 + threadIdx.x;   // over 512*512, exact grid
    int i = idx >> 9;          // 0..511
    int j = idx & 511;
    float2 o;
    if (j > i) { o.x = W_hh[idx]; o.y = b_hh[idx]; }  // i<=510 whenever j>i
    else       { o.x = 0.0f;      o.y = -1.0f;     }
    wb[idx] = o;
}

// ---------------------------------------------------------------------------
// fp32 GEMM: C = act(A[M,K] @ B[K,N] + bias). BM=BN=BK=32, 256 threads,
// 2x2 microtile, grid (M/32)x(N/32) = 512 blocks -> 2 blocks/CU
// (launch_bounds(256,2)); independent per-block barriers overlap.
// LDS: As[m][k] stride 36 (b128 reads along k, conflict-free reads),
//      Bs[k][n] stride 34 (b64 reads, conflict-free).
// Register-relay prefetch of next K-tile pinned with sched_barrier.
// ---------------------------------------------------------------------------
template <bool ACT>
__global__ __launch_bounds__(256, 2)
void gemm_kernel(const float* __restrict__ A,
                 const float* __restrict__ Bm,
                 const float* __restrict__ bias,
                 float* __restrict__ C,
                 int M, int N, int K) {
    __shared__ float As[32][36];   // [m][k]
    __shared__ float Bs[32][34];   // [k][n]

    const int tid = threadIdx.x;
    const int bm = blockIdx.x * 32;
    const int bn = blockIdx.y * 32;
    const int ty = tid >> 4;        // 0..15 -> rows 2ty..2ty+1
    const int tx = tid & 15;        // cols 2tx..2tx+1
    const int sr = tid >> 3;        // stage row/k 0..31
    const int sc = (tid & 7) * 4;   // stage col 0..28

    float4 a0, b0;                  // relay registers
    auto stage = [&](int kt) {
        a0 = *(const float4*)&A[(size_t)(bm + sr) * K + kt + sc];
        b0 = *(const float4*)&Bm[(size_t)(kt + sr) * N + bn + sc];
    };

    float acc00 = 0.f, acc01 = 0.f, acc10 = 0.f, acc11 = 0.f;

    stage(0);
    for (int kt = 0; kt < K; kt += 32) {
        __syncthreads();
        *(float4*)&As[sr][sc] = a0;
        *(float4*)&Bs[sr][sc] = b0;
        __syncthreads();
        if (kt + 32 < K) stage(kt + 32);
        __builtin_amdgcn_sched_barrier(0);

        #pragma unroll
        for (int k4 = 0; k4 < 32; k4 += 4) {
            const float4 aA = *(const float4*)&As[2 * ty][k4];
            const float4 aB = *(const float4*)&As[2 * ty + 1][k4];
            #pragma unroll
            for (int u = 0; u < 4; ++u) {
                const float2 bf = *(const float2*)&Bs[k4 + u][2 * tx];
                const float av = (u == 0) ? aA.x : (u == 1) ? aA.y
                               : (u == 2) ? aA.z : aA.w;
                const float bv = (u == 0) ? aB.x : (u == 1) ? aB.y
                               : (u == 2) ? aB.z : aB.w;
                acc00 = fmaf(av, bf.x, acc00);
                acc01 = fmaf(av, bf.y, acc01);
                acc10 = fmaf(bv, bf.x, acc10);
                acc11 = fmaf(bv, bf.y, acc11);
            }
        }
    }

    const int col = bn + 2 * tx;
    const float2 bias2 = *(const float2*)&bias[col];
    float2 v0, v1;
    v0.x = acc00 + bias2.x; v0.y = acc01 + bias2.y;
    v1.x = acc10 + bias2.x; v1.y = acc11 + bias2.y;
    if (ACT) {
        v0.x = fmaxf(v0.x, 0.f); v0.x *= v0.x;
        v0.y = fmaxf(v0.y, 0.f); v0.y *= v0.y;
        v1.x = fmaxf(v1.x, 0.f); v1.x *= v1.x;
        v1.y = fmaxf(v1.y, 0.f); v1.y *= v1.y;
    }
    *(float2*)&C[(size_t)(bm + 2 * ty) * N + col]     = v0;
    *(float2*)&C[(size_t)(bm + 2 * ty + 1) * N + col] = v1;
}

// ---------------------------------------------------------------------------
// Blocked triangular scan v5. 256 blocks x 512 threads (8 waves, 2/SIMD).
// Block owns 4 batch rows; wave w owns column-chunk w (cols 64w..64w+63)
// for ALL 4 rows -> per-wave state is 4 named scalars, zero runtime
// register indexing (the v4 spill bug). Phase C = 0..7:
//   - wave C: 64-step diag on its chunk (4 independent readlane chains),
//     weights from global via 8-deep static register ring; publish to hpub.
//   - waves w>C prefetch their rect ring DURING the diag (pre-barrier).
//   - one barrier; waves w>C apply one 64x64 rect tile (source chunk C),
//     weights streamed from L2-hot global, h_i broadcast via readlane.
// ---------------------------------------------------------------------------
__global__ __launch_bounds__(512)
void scan_kernel(const float2* __restrict__ wb, float* __restrict__ h) {
    __shared__ float hpub[8][4][64];   // 8 KB

    const int tid  = threadIdx.x;
    const int lane = tid & 63;
    const int wv   = tid >> 6;         // 0..7, owned chunk
    const int r0   = blockIdx.x * 4;

    const size_t hb = (size_t)r0 * HH + 64 * wv + lane;
    float hr0 = h[hb];
    float hr1 = h[hb + HH];
    float hr2 = h[hb + 2 * HH];
    float hr3 = h[hb + 3 * HH];

    #pragma unroll 1
    for (int C = 0; C < 8; ++C) {
        // weights for this phase, this wave: rows [64C,64C+64), col 64wv+lane
        const float2* bp = wb + (size_t)(64 * C) * HH + 64 * wv + lane;
        float2 ring[8];

        if (wv >= C) {                 // prefetch ring (rect waves: overlaps diag)
            #pragma unroll
            for (int u = 0; u < 8; ++u) ring[u] = bp[(size_t)u * HH];
        }

        if (wv == C) {
            // ---- diag: 64 serial steps, 4 rows interleaved
            #pragma unroll 1
            for (int i8 = 0; i8 < 8; ++i8) {
                #pragma unroll
                for (int u = 0; u < 8; ++u) {
                    const int i = i8 * 8 + u;
                    const float2 w2 = ring[u];
                    if (i8 < 7) ring[u] = bp[(size_t)(i + 8) * HH];
                    float t;
                    t = fmaf(rl(hr0, i), w2.x, w2.y); t = fmaxf(t, 0.f); hr0 = fmaf(t, t, hr0);
                    t = fmaf(rl(hr1, i), w2.x, w2.y); t = fmaxf(t, 0.f); hr1 = fmaf(t, t, hr1);
                    t = fmaf(rl(hr2, i), w2.x, w2.y); t = fmaxf(t, 0.f); hr2 = fmaf(t, t, hr2);
                    t = fmaf(rl(hr3, i), w2.x, w2.y); t = fmaxf(t, 0.f); hr3 = fmaf(t, t, hr3);
                }
            }
            hpub[C][0][lane] = hr0;
            hpub[C][1][lane] = hr1;
            hpub[C][2][lane] = hr2;
            hpub[C][3][lane] = hr3;
        }

        __syncthreads();               // hpub[C] ready (uniform: 1/phase/wave)

        if (wv > C) {
            // ---- rect: dependency-free, one 64x64 tile
            const float h0 = hpub[C][0][lane];
            const float h1 = hpub[C][1][lane];
            const float h2 = hpub[C][2][lane];
            const float h3 = hpub[C][3][lane];
            #pragma unroll 1
            for (int i8 = 0; i8 < 8; ++i8) {
                #pragma unroll
                for (int u = 0; u < 8; ++u) {
                    const int i = i8 * 8 + u;
                    const float2 w2 = ring[u];
                    if (i8 < 7) ring[u] = bp[(size_t)(i + 8) * HH];
                    float t;
                    t = fmaf(rl(h0, i), w2.x, w2.y); t = fmaxf(t, 0.f); hr0 = fmaf(t, t, hr0);
                    t = fmaf(rl(h1, i), w2.x, w2.y); t = fmaxf(t, 0.f); hr1 = fmaf(t, t, hr1);
                    t = fmaf(rl(h2, i), w2.x, w2.y); t = fmaxf(t, 0.f); hr2 = fmaf(t, t, hr2);
                    t = fmaf(rl(h3, i), w2.x, w2.y); t = fmaxf(t, 0.f); hr3 = fmaf(t, t, hr3);
                }
            }
        }
    }

    h[hb]          = hr0;
    h[hb + HH]     = hr1;
    h[hb + 2 * HH] = hr2;
    h[hb + 3 * HH] = hr3;
}

// ---------------------------------------------------------------------------
extern "C" void kernel_launch(void* const* d_in, const int* in_sizes, int n_in,
                              void* d_out, int out_size, void* d_ws, size_t ws_size,
                              hipStream_t stream) {
    const float* x     = (const float*)d_in[0];
    const float* W_in  = (const float*)d_in[1];
    const float* b_in  = (const float*)d_in[2];
    const float* W_hh  = (const float*)d_in[3];
    const float* b_hh  = (const float*)d_in[4];
    const float* W_out = (const float*)d_in[5];
    const float* b_out = (const float*)d_in[6];
    float* out = (float*)d_out;

    // workspace: [0,2MB) wb (512x512 float2), [2MB,4MB) h (1024x512 f32)
    float2* wb = (float2*)d_ws;
    float*  h  = (float*)((char*)d_ws + (1u << 21));

    // 1) masked padded weights
    prep_kernel<<<dim3(1024), dim3(256), 0, stream>>>(W_hh, b_hh, wb);

    // 2) h0 = relu^2(x @ W_in + b_in)
    gemm_kernel<true><<<dim3(B_SZ / 32, HH / 32), dim3(256), 0, stream>>>(
        x, W_in, b_in, h, B_SZ, HH, DIN);

    // 3) blocked triangular scan, in-place on h
    scan_kernel<<<dim3(256), dim3(512), 0, stream>>>(wb, h);

    // 4) out = h @ W_out + b_out
    gemm_kernel<false><<<dim3(B_SZ / 32, DOUT / 32), dim3(256), 0, stream>>>(
        h, W_out, b_out, out, B_SZ, DOUT, HH);
}

// Round 6
// 183.448 us; speedup vs baseline: 1.4972x; 1.1868x over previous
//
#include <hip/hip_runtime.h>
#include <hip/hip_fp16.h>

#define B_SZ 1024
#define DIN 512
#define HH 512   // H
#define DOUT 512

typedef unsigned int uint32;

__device__ __forceinline__ float rl(float x, int i) {
    return __uint_as_float(__builtin_amdgcn_readlane(__float_as_uint(x), i));
}

// ---------------------------------------------------------------------------
// prep: pack wb[i][j] = (j>i) ? {half(W_hh[i][j]), half(b_hh[i][j])}
//                            : {0, -1}  into one dword. Padded to 512 rows.
// relu(0*h - 1) = 0 -> masked entries contribute nothing.
// ---------------------------------------------------------------------------
__global__ __launch_bounds__(256)
void prep_kernel(const float* __restrict__ W_hh,
                 const float* __restrict__ b_hh,
                 uint32* __restrict__ wb) {
    int idx = blockIdx.x * 256 + threadIdx.x;   // over 512*512, exact grid
    int i = idx >> 9;          // 0..511
    int j = idx & 511;
    float w, b;
    if (j > i) { w = W_hh[idx]; b = b_hh[idx]; }   // i<=510 whenever j>i
    else       { w = 0.0f;      b = -1.0f;     }
    __half2 p = __floats2half2_rn(w, b);           // low = w, high = b
    wb[idx] = *(const uint32*)&p;
}

// ---------------------------------------------------------------------------
// fp32 GEMM: C = act(A[M,K] @ B[K,N] + bias). BM=64, BN=32, BK=32,
// 256 threads, 4x2 microtile. LDS: As[k][m] stride 65 -> A-reads are
// 4-address broadcasts (conflict-free); Bs[k][n] stride 33 -> B-reads
// conflict-free. Register-relay prefetch of next K-tile + sched_barrier.
// Grid (M/64)x(N/32) = 256 blocks -> 1 block/CU, 4 waves.
// ---------------------------------------------------------------------------
template <bool ACT>
__global__ __launch_bounds__(256)
void gemm_kernel(const float* __restrict__ A,
                 const float* __restrict__ Bm,
                 const float* __restrict__ bias,
                 float* __restrict__ C,
                 int M, int N, int K) {
    __shared__ float As[32][65];   // [k][m]
    __shared__ float Bs[32][33];   // [k][n]

    const int tid = threadIdx.x;
    const int bm = blockIdx.x * 64;
    const int bn = blockIdx.y * 32;
    const int ty = tid >> 4;        // 0..15 -> m rows 4ty..4ty+3 (wave: 4 ty)
    const int tx = tid & 15;        // n cols 2tx..2tx+1
    const int am = tid >> 2;        // A stage m 0..63
    const int ak = (tid & 3) * 8;   // A stage k 0,8,16,24
    const int bk = tid >> 3;        // B stage k 0..31
    const int bc = (tid & 7) * 4;   // B stage n 0..28

    float4 a0, a1, b0;              // relay registers
    auto stage = [&](int kt) {
        a0 = *(const float4*)&A[(size_t)(bm + am) * K + kt + ak];
        a1 = *(const float4*)&A[(size_t)(bm + am) * K + kt + ak + 4];
        b0 = *(const float4*)&Bm[(size_t)(kt + bk) * N + bn + bc];
    };

    float acc[4][2] = {};

    stage(0);
    for (int kt = 0; kt < K; kt += 32) {
        __syncthreads();
        #pragma unroll
        for (int u = 0; u < 4; ++u) {
            As[ak + u][am]     = ((const float*)&a0)[u];
            As[ak + 4 + u][am] = ((const float*)&a1)[u];
        }
        *(float4*)&Bs[bk][bc] = b0;
        __syncthreads();
        if (kt + 32 < K) stage(kt + 32);
        __builtin_amdgcn_sched_barrier(0);

        #pragma unroll
        for (int k = 0; k < 32; ++k) {
            const float4 a = *(const float4*)&As[k][4 * ty];
            const float2 b = *(const float2*)&Bs[k][2 * tx];
            acc[0][0] = fmaf(a.x, b.x, acc[0][0]);
            acc[0][1] = fmaf(a.x, b.y, acc[0][1]);
            acc[1][0] = fmaf(a.y, b.x, acc[1][0]);
            acc[1][1] = fmaf(a.y, b.y, acc[1][1]);
            acc[2][0] = fmaf(a.z, b.x, acc[2][0]);
            acc[2][1] = fmaf(a.z, b.y, acc[2][1]);
            acc[3][0] = fmaf(a.w, b.x, acc[3][0]);
            acc[3][1] = fmaf(a.w, b.y, acc[3][1]);
        }
    }

    const int col = bn + 2 * tx;
    const float2 bias2 = *(const float2*)&bias[col];
    #pragma unroll
    for (int j = 0; j < 4; ++j) {
        float2 v;
        v.x = acc[j][0] + bias2.x;
        v.y = acc[j][1] + bias2.y;
        if (ACT) {
            v.x = fmaxf(v.x, 0.f); v.x *= v.x;
            v.y = fmaxf(v.y, 0.f); v.y *= v.y;
        }
        *(float2*)&C[(size_t)(bm + 4 * ty + j) * N + col] = v;
    }
}

// ---------------------------------------------------------------------------
// Blocked triangular scan v6: all weights consumed from LDS.
// 256 blocks x 512 threads (8 waves). Block owns 4 batch rows; wave w owns
// column-chunk w. Per phase C:
//   stage: all waves bulk-copy band rows [64C,64C+64) x cols [64C,512)
//          (packed fp16 pairs, 4B/entry) into a 128 KB LDS band.
//   diag (wave C): 64 serial steps, weights via 8-deep ds_read ring
//          (fine-grained lgkmcnt), publish chunk to hpub.
//   rect (waves >C): one 64x64 tile each, weights via batched ds_read_b32
//          (zero serial dependency), h broadcast via readlane.
// 3 barriers/phase. No global loads in any hot loop.
// ---------------------------------------------------------------------------
template <int C>
__device__ __forceinline__ void phase_fn(const uint32* __restrict__ wb,
                                         uint32* __restrict__ band,
                                         float* __restrict__ hpub,
                                         float& hr0, float& hr1,
                                         float& hr2, float& hr3,
                                         int lane, int wv, int tid) {
    constexpr int WC = 512 - 64 * C;       // band width (dwords)
    constexpr int W4 = WC / 4;             // width in uint4
    constexpr int NQ = (64 * W4) / 512;    // uint4 chunks per thread

    // ---- stage band: global (L2-hot) -> LDS, bulk independent copies
    {
        const uint32* srow = wb + (size_t)(64 * C) * 512 + 64 * C;
        #pragma unroll
        for (int q = 0; q < NQ; ++q) {
            const int e4 = tid + 512 * q;
            const int r  = e4 / W4;                 // compile-time divisor
            const int c4 = e4 - r * W4;
            const uint4 v = *(const uint4*)&srow[(size_t)r * 512 + 4 * c4];
            *(uint4*)&band[r * WC + 4 * c4] = v;
        }
    }
    __syncthreads();                       // band ready

    if (wv == C) {
        // ---- diag: 64 serial steps, 4 rows interleaved, LDS ring
        uint32 ring[8];
        #pragma unroll
        for (int u = 0; u < 8; ++u) ring[u] = band[u * WC + lane];
        #pragma unroll 1
        for (int i8 = 0; i8 < 8; ++i8) {
            #pragma unroll
            for (int u = 0; u < 8; ++u) {
                const int i = 8 * i8 + u;
                const float2 w = __half22float2(*(const __half2*)&ring[u]);
                if (i8 < 7) ring[u] = band[(i + 8) * WC + lane];
                float t;
                t = fmaf(rl(hr0, i), w.x, w.y); t = fmaxf(t, 0.f); hr0 = fmaf(t, t, hr0);
                t = fmaf(rl(hr1, i), w.x, w.y); t = fmaxf(t, 0.f); hr1 = fmaf(t, t, hr1);
                t = fmaf(rl(hr2, i), w.x, w.y); t = fmaxf(t, 0.f); hr2 = fmaf(t, t, hr2);
                t = fmaf(rl(hr3, i), w.x, w.y); t = fmaxf(t, 0.f); hr3 = fmaf(t, t, hr3);
            }
        }
        hpub[0 * 64 + lane] = hr0;
        hpub[1 * 64 + lane] = hr1;
        hpub[2 * 64 + lane] = hr2;
        hpub[3 * 64 + lane] = hr3;
    }
    __syncthreads();                       // hpub ready

    if (wv > C) {
        // ---- rect: one 64x64 tile, no serial dependency
        const int cb = 64 * (wv - C);
        const float h0 = hpub[0 * 64 + lane];
        const float h1 = hpub[1 * 64 + lane];
        const float h2 = hpub[2 * 64 + lane];
        const float h3 = hpub[3 * 64 + lane];
        #pragma unroll 1
        for (int i8 = 0; i8 < 8; ++i8) {
            uint32 wr8[8];
            #pragma unroll
            for (int u = 0; u < 8; ++u)
                wr8[u] = band[(8 * i8 + u) * WC + cb + lane];
            #pragma unroll
            for (int u = 0; u < 8; ++u) {
                const int i = 8 * i8 + u;
                const float2 w = __half22float2(*(const __half2*)&wr8[u]);
                float t;
                t = fmaf(rl(h0, i), w.x, w.y); t = fmaxf(t, 0.f); hr0 = fmaf(t, t, hr0);
                t = fmaf(rl(h1, i), w.x, w.y); t = fmaxf(t, 0.f); hr1 = fmaf(t, t, hr1);
                t = fmaf(rl(h2, i), w.x, w.y); t = fmaxf(t, 0.f); hr2 = fmaf(t, t, hr2);
                t = fmaf(rl(h3, i), w.x, w.y); t = fmaxf(t, 0.f); hr3 = fmaf(t, t, hr3);
            }
        }
    }
    __syncthreads();                       // band free for next phase
}

__global__ __launch_bounds__(512)
void scan_kernel(const uint32* __restrict__ wb, float* __restrict__ h) {
    __shared__ uint32 band[64 * 512];      // 128 KB
    __shared__ float  hpub[4 * 64];        // 1 KB

    const int tid  = threadIdx.x;
    const int lane = tid & 63;
    const int wv   = tid >> 6;             // 0..7, owned column chunk
    const int r0   = blockIdx.x * 4;

    const size_t hb = (size_t)r0 * HH + 64 * wv + lane;
    float hr0 = h[hb];
    float hr1 = h[hb + HH];
    float hr2 = h[hb + 2 * HH];
    float hr3 = h[hb + 3 * HH];

    phase_fn<0>(wb, band, hpub, hr0, hr1, hr2, hr3, lane, wv, tid);
    phase_fn<1>(wb, band, hpub, hr0, hr1, hr2, hr3, lane, wv, tid);
    phase_fn<2>(wb, band, hpub, hr0, hr1, hr2, hr3, lane, wv, tid);
    phase_fn<3>(wb, band, hpub, hr0, hr1, hr2, hr3, lane, wv, tid);
    phase_fn<4>(wb, band, hpub, hr0, hr1, hr2, hr3, lane, wv, tid);
    phase_fn<5>(wb, band, hpub, hr0, hr1, hr2, hr3, lane, wv, tid);
    phase_fn<6>(wb, band, hpub, hr0, hr1, hr2, hr3, lane, wv, tid);
    phase_fn<7>(wb, band, hpub, hr0, hr1, hr2, hr3, lane, wv, tid);

    h[hb]          = hr0;
    h[hb + HH]     = hr1;
    h[hb + 2 * HH] = hr2;
    h[hb + 3 * HH] = hr3;
}

// ---------------------------------------------------------------------------
extern "C" void kernel_launch(void* const* d_in, const int* in_sizes, int n_in,
                              void* d_out, int out_size, void* d_ws, size_t ws_size,
                              hipStream_t stream) {
    const float* x     = (const float*)d_in[0];
    const float* W_in  = (const float*)d_in[1];
    const float* b_in  = (const float*)d_in[2];
    const float* W_hh  = (const float*)d_in[3];
    const float* b_hh  = (const float*)d_in[4];
    const float* W_out = (const float*)d_in[5];
    const float* b_out = (const float*)d_in[6];
    float* out = (float*)d_out;

    // workspace: [0,1MB) packed wb (512x512 dwords), [1MB,3MB) h (1024x512 f32)
    uint32* wb = (uint32*)d_ws;
    float*  h  = (float*)((char*)d_ws + (1u << 20));

    // 1) masked packed fp16-pair weights
    prep_kernel<<<dim3(1024), dim3(256), 0, stream>>>(W_hh, b_hh, wb);

    // 2) h0 = relu^2(x @ W_in + b_in)
    gemm_kernel<true><<<dim3(B_SZ / 64, HH / 32), dim3(256), 0, stream>>>(
        x, W_in, b_in, h, B_SZ, HH, DIN);

    // 3) blocked triangular scan, in-place on h
    scan_kernel<<<dim3(256), dim3(512), 0, stream>>>(wb, h);

    // 4) out = h @ W_out + b_out
    gemm_kernel<false><<<dim3(B_SZ / 64, DOUT / 32), dim3(256), 0, stream>>>(
        h, W_out, b_out, out, B_SZ, DOUT, HH);
}

// Round 7
// 178.305 us; speedup vs baseline: 1.5404x; 1.0288x over previous
//
#include <hip/hip_runtime.h>
#include <hip/hip_fp16.h>

#define B_SZ 1024
#define DIN 512
#define HH 512   // H
#define DOUT 512

typedef unsigned int uint32;

__device__ __forceinline__ float rl(float x, int i) {
    return __uint_as_float(__builtin_amdgcn_readlane(__float_as_uint(x), i));
}

// ---------------------------------------------------------------------------
// prep: pack wb[i][j] = (j>i) ? {half(W_hh[i][j]), half(b_hh[i][j])}
//                            : {0, -1}  into one dword. Padded to 512 rows.
// relu(0*h - 1) = 0 -> masked entries contribute nothing.
// ---------------------------------------------------------------------------
__global__ __launch_bounds__(256)
void prep_kernel(const float* __restrict__ W_hh,
                 const float* __restrict__ b_hh,
                 uint32* __restrict__ wb) {
    int idx = blockIdx.x * 256 + threadIdx.x;   // over 512*512, exact grid
    int i = idx >> 9;
    int j = idx & 511;
    float w, b;
    if (j > i) { w = W_hh[idx]; b = b_hh[idx]; }
    else       { w = 0.0f;      b = -1.0f;     }
    __half2 p = __floats2half2_rn(w, b);        // low = w, high = b
    wb[idx] = *(const uint32*)&p;
}

// ---------------------------------------------------------------------------
// fp32 GEMM, LDS double-buffered: ONE barrier per K-tile (no drain-stall
// pair, no sched_barrier -- m141 showed order-pinning regresses).
// BM=64, BN=32, BK=32, 256 threads, 4x2 microtile, grid 16x16=256 blocks.
// As[buf][k][m] stride 65: A-reads are 4-addr broadcasts, conflict-free.
// Bs[buf][k][n] stride 33: B-reads conflict-free.
// Next tile's global loads issue right after the barrier; LDS commit happens
// AFTER the FMA loop, so vmcnt slack = the whole compute loop.
// ---------------------------------------------------------------------------
template <bool ACT>
__global__ __launch_bounds__(256)
void gemm_kernel(const float* __restrict__ A,
                 const float* __restrict__ Bm,
                 const float* __restrict__ bias,
                 float* __restrict__ C,
                 int M, int N, int K) {
    __shared__ float As[2][32][65];
    __shared__ float Bs[2][32][33];

    const int tid = threadIdx.x;
    const int bm = blockIdx.x * 64;
    const int bn = blockIdx.y * 32;
    const int ty = tid >> 4;        // m rows 4ty..4ty+3
    const int tx = tid & 15;        // n cols 2tx..2tx+1
    const int am = tid >> 2;        // A stage m 0..63
    const int ak = (tid & 3) * 8;   // A stage k 0,8,16,24
    const int bk = tid >> 3;        // B stage k 0..31
    const int bc = (tid & 7) * 4;   // B stage n 0..28

    float4 a0, a1, b0;
    auto stage = [&](int kt) {
        a0 = *(const float4*)&A[(size_t)(bm + am) * K + kt + ak];
        a1 = *(const float4*)&A[(size_t)(bm + am) * K + kt + ak + 4];
        b0 = *(const float4*)&Bm[(size_t)(kt + bk) * N + bn + bc];
    };
    auto commit = [&](int buf) {
        #pragma unroll
        for (int u = 0; u < 4; ++u) {
            As[buf][ak + u][am]     = ((const float*)&a0)[u];
            As[buf][ak + 4 + u][am] = ((const float*)&a1)[u];
        }
        *(float4*)&Bs[buf][bk][bc] = b0;
    };

    float acc[4][2] = {};

    stage(0);
    commit(0);
    int cur = 0;
    for (int kt = 0; kt < K; kt += 32) {
        __syncthreads();                     // buf[cur] ready for all waves
        if (kt + 32 < K) stage(kt + 32);     // overlaps the FMA loop below

        #pragma unroll
        for (int k = 0; k < 32; ++k) {
            const float4 a = *(const float4*)&As[cur][k][4 * ty];
            const float2 b = *(const float2*)&Bs[cur][k][2 * tx];
            acc[0][0] = fmaf(a.x, b.x, acc[0][0]);
            acc[0][1] = fmaf(a.x, b.y, acc[0][1]);
            acc[1][0] = fmaf(a.y, b.x, acc[1][0]);
            acc[1][1] = fmaf(a.y, b.y, acc[1][1]);
            acc[2][0] = fmaf(a.z, b.x, acc[2][0]);
            acc[2][1] = fmaf(a.z, b.y, acc[2][1]);
            acc[3][0] = fmaf(a.w, b.x, acc[3][0]);
            acc[3][1] = fmaf(a.w, b.y, acc[3][1]);
        }
        if (kt + 32 < K) commit(cur ^ 1);    // idle buffer; readers passed barrier
        cur ^= 1;
    }

    const int col = bn + 2 * tx;
    const float2 bias2 = *(const float2*)&bias[col];
    #pragma unroll
    for (int j = 0; j < 4; ++j) {
        float2 v;
        v.x = acc[j][0] + bias2.x;
        v.y = acc[j][1] + bias2.y;
        if (ACT) {
            v.x = fmaxf(v.x, 0.f); v.x *= v.x;
            v.y = fmaxf(v.y, 0.f); v.y *= v.y;
        }
        *(float2*)&C[(size_t)(bm + 4 * ty + j) * N + col] = v;
    }
}

// ---------------------------------------------------------------------------
// Blocked triangular scan v7: 3-window pipeline, no idle waves.
// 256 blocks x 512 threads (8 waves). Block owns 4 batch rows; wave w owns
// column-chunk w. Band for phase C = rows [64C,64C+64) x cols [64C,512),
// split bandA (rows 0-31) / bandB (rows 32-63), fp16-pair packed.
// Phase C windows (3 barriers):
//  W1: wave C diag steps 0-31 (bandA), partial h publish | 7 waves stage bandB
//  W2: wave C diag steps 32-63 (bandB), publish lanes>=32 | waves>C rect i=0..31 (bandA)
//  W3: waves>C rect i=32..63 (bandB) | waves<=C stage next phase's bandA
// ---------------------------------------------------------------------------
template <int C>
__device__ __forceinline__ void phase_fn(const uint32* __restrict__ wb,
                                         uint32* __restrict__ bandA,
                                         uint32* __restrict__ bandB,
                                         float* __restrict__ hpub,
                                         float& hr0, float& hr1,
                                         float& hr2, float& hr3,
                                         int lane, int wv) {
    constexpr int WC = 512 - 64 * C;       // band width (dwords)
    constexpr int W4 = WC / 4;
    const uint32* brow = wb + (size_t)(64 * C) * 512 + 64 * C;

    __syncthreads();                       // barrier1: bandA(C) staged

    // ---- W1
    if (wv == C) {
        // diag steps 0..31 from bandA
        uint32 ring[8];
        #pragma unroll
        for (int u = 0; u < 8; ++u) ring[u] = bandA[u * WC + lane];
        #pragma unroll 1
        for (int i8 = 0; i8 < 4; ++i8) {
            #pragma unroll
            for (int u = 0; u < 8; ++u) {
                const int i = 8 * i8 + u;
                const float2 w = __half22float2(*(const __half2*)&ring[u]);
                if (i8 < 3) ring[u] = bandA[(i + 8) * WC + lane];
                float t;
                t = fmaf(rl(hr0, i), w.x, w.y); t = fmaxf(t, 0.f); hr0 = fmaf(t, t, hr0);
                t = fmaf(rl(hr1, i), w.x, w.y); t = fmaxf(t, 0.f); hr1 = fmaf(t, t, hr1);
                t = fmaf(rl(hr2, i), w.x, w.y); t = fmaxf(t, 0.f); hr2 = fmaf(t, t, hr2);
                t = fmaf(rl(hr3, i), w.x, w.y); t = fmaxf(t, 0.f); hr3 = fmaf(t, t, hr3);
            }
        }
        hpub[0 * 64 + lane] = hr0;         // lanes 0..32 now final
        hpub[1 * 64 + lane] = hr1;
        hpub[2 * 64 + lane] = hr2;
        hpub[3 * 64 + lane] = hr3;
    } else {
        // stage bandB: rows 32..63 of band C (7 waves, 448 threads)
        const int p = (wv < C) ? wv : wv - 1;
        const int pid = p * 64 + lane;
        constexpr int TOT = 32 * W4;
        #pragma unroll 4
        for (int e4 = pid; e4 < TOT; e4 += 448) {
            const int r = e4 / W4;
            const int c4 = e4 - r * W4;
            *(uint4*)&bandB[r * WC + 4 * c4] =
                *(const uint4*)&brow[(size_t)(32 + r) * 512 + 4 * c4];
        }
    }

    __syncthreads();                       // barrier2: bandB + hpub(0..31)

    // ---- W2
    if (wv == C) {
        // diag steps 32..63 from bandB
        uint32 ring[8];
        #pragma unroll
        for (int u = 0; u < 8; ++u) ring[u] = bandB[u * WC + lane];
        #pragma unroll 1
        for (int i8 = 0; i8 < 4; ++i8) {
            #pragma unroll
            for (int u = 0; u < 8; ++u) {
                const int i = 32 + 8 * i8 + u;
                const float2 w = __half22float2(*(const __half2*)&ring[u]);
                if (i8 < 3) ring[u] = bandB[(8 * i8 + u + 8) * WC + lane];
                float t;
                t = fmaf(rl(hr0, i), w.x, w.y); t = fmaxf(t, 0.f); hr0 = fmaf(t, t, hr0);
                t = fmaf(rl(hr1, i), w.x, w.y); t = fmaxf(t, 0.f); hr1 = fmaf(t, t, hr1);
                t = fmaf(rl(hr2, i), w.x, w.y); t = fmaxf(t, 0.f); hr2 = fmaf(t, t, hr2);
                t = fmaf(rl(hr3, i), w.x, w.y); t = fmaxf(t, 0.f); hr3 = fmaf(t, t, hr3);
            }
        }
        if (lane >= 32) {                  // lanes 0..31 already published
            hpub[0 * 64 + lane] = hr0;
            hpub[1 * 64 + lane] = hr1;
            hpub[2 * 64 + lane] = hr2;
            hpub[3 * 64 + lane] = hr3;
        }
    } else if (wv > C) {
        // rect i = 0..31 from bandA
        const int cb = 64 * (wv - C);
        const float h0 = hpub[0 * 64 + lane];
        const float h1 = hpub[1 * 64 + lane];
        const float h2 = hpub[2 * 64 + lane];
        const float h3 = hpub[3 * 64 + lane];
        #pragma unroll 1
        for (int i8 = 0; i8 < 4; ++i8) {
            uint32 wr8[8];
            #pragma unroll
            for (int u = 0; u < 8; ++u)
                wr8[u] = bandA[(8 * i8 + u) * WC + cb + lane];
            #pragma unroll
            for (int u = 0; u < 8; ++u) {
                const int i = 8 * i8 + u;
                const float2 w = __half22float2(*(const __half2*)&wr8[u]);
                float t;
                t = fmaf(rl(h0, i), w.x, w.y); t = fmaxf(t, 0.f); hr0 = fmaf(t, t, hr0);
                t = fmaf(rl(h1, i), w.x, w.y); t = fmaxf(t, 0.f); hr1 = fmaf(t, t, hr1);
                t = fmaf(rl(h2, i), w.x, w.y); t = fmaxf(t, 0.f); hr2 = fmaf(t, t, hr2);
                t = fmaf(rl(h3, i), w.x, w.y); t = fmaxf(t, 0.f); hr3 = fmaf(t, t, hr3);
            }
        }
    }

    __syncthreads();                       // barrier3: hpub full, bandA free

    // ---- W3
    if (wv > C) {
        // rect i = 32..63 from bandB
        const int cb = 64 * (wv - C);
        const float h0 = hpub[0 * 64 + lane];
        const float h1 = hpub[1 * 64 + lane];
        const float h2 = hpub[2 * 64 + lane];
        const float h3 = hpub[3 * 64 + lane];
        #pragma unroll 1
        for (int i8 = 0; i8 < 4; ++i8) {
            uint32 wr8[8];
            #pragma unroll
            for (int u = 0; u < 8; ++u)
                wr8[u] = bandB[(8 * i8 + u) * WC + cb + lane];
            #pragma unroll
            for (int u = 0; u < 8; ++u) {
                const int i = 32 + 8 * i8 + u;
                const float2 w = __half22float2(*(const __half2*)&wr8[u]);
                float t;
                t = fmaf(rl(h0, i), w.x, w.y); t = fmaxf(t, 0.f); hr0 = fmaf(t, t, hr0);
                t = fmaf(rl(h1, i), w.x, w.y); t = fmaxf(t, 0.f); hr1 = fmaf(t, t, hr1);
                t = fmaf(rl(h2, i), w.x, w.y); t = fmaxf(t, 0.f); hr2 = fmaf(t, t, hr2);
                t = fmaf(rl(h3, i), w.x, w.y); t = fmaxf(t, 0.f); hr3 = fmaf(t, t, hr3);
            }
        }
    } else if (C < 7) {
        // stage next phase's bandA: rows 0..31 of band C+1 (waves 0..C)
        constexpr int WN = WC - 64;
        constexpr int WN4 = WN / 4;
        constexpr int TOTN = 32 * WN4;
        const uint32* nrow = wb + (size_t)(64 * (C + 1)) * 512 + 64 * (C + 1);
        const int pid = wv * 64 + lane;
        #pragma unroll 2
        for (int e4 = pid; e4 < TOTN; e4 += 64 * (C + 1)) {
            const int r = e4 / WN4;
            const int c4 = e4 - r * WN4;
            *(uint4*)&bandA[r * WN + 4 * c4] =
                *(const uint4*)&nrow[(size_t)r * 512 + 4 * c4];
        }
    }
}

__global__ __launch_bounds__(512)
void scan_kernel(const uint32* __restrict__ wb, float* __restrict__ h) {
    __shared__ uint32 bandA[32 * 512];     // 64 KB: band rows 0..31
    __shared__ uint32 bandB[32 * 512];     // 64 KB: band rows 32..63
    __shared__ float  hpub[4 * 64];        // 1 KB

    const int tid  = threadIdx.x;
    const int lane = tid & 63;
    const int wv   = tid >> 6;             // owned column chunk
    const int r0   = blockIdx.x * 4;

    const size_t hb = (size_t)r0 * HH + 64 * wv + lane;
    float hr0 = h[hb];
    float hr1 = h[hb + HH];
    float hr2 = h[hb + 2 * HH];
    float hr3 = h[hb + 3 * HH];

    // preload: all 8 waves stage band0 rows 0..31 into bandA (64 KB)
    #pragma unroll 4
    for (int e4 = tid; e4 < 32 * 128; e4 += 512) {
        const int r = e4 >> 7;
        const int c4 = e4 & 127;
        *(uint4*)&bandA[r * 512 + 4 * c4] =
            *(const uint4*)&wb[(size_t)r * 512 + 4 * c4];
    }

    phase_fn<0>(wb, bandA, bandB, hpub, hr0, hr1, hr2, hr3, lane, wv);
    phase_fn<1>(wb, bandA, bandB, hpub, hr0, hr1, hr2, hr3, lane, wv);
    phase_fn<2>(wb, bandA, bandB, hpub, hr0, hr1, hr2, hr3, lane, wv);
    phase_fn<3>(wb, bandA, bandB, hpub, hr0, hr1, hr2, hr3, lane, wv);
    phase_fn<4>(wb, bandA, bandB, hpub, hr0, hr1, hr2, hr3, lane, wv);
    phase_fn<5>(wb, bandA, bandB, hpub, hr0, hr1, hr2, hr3, lane, wv);
    phase_fn<6>(wb, bandA, bandB, hpub, hr0, hr1, hr2, hr3, lane, wv);
    phase_fn<7>(wb, bandA, bandB, hpub, hr0, hr1, hr2, hr3, lane, wv);

    h[hb]          = hr0;
    h[hb + HH]     = hr1;
    h[hb + 2 * HH] = hr2;
    h[hb + 3 * HH] = hr3;
}

// ---------------------------------------------------------------------------
extern "C" void kernel_launch(void* const* d_in, const int* in_sizes, int n_in,
                              void* d_out, int out_size, void* d_ws, size_t ws_size,
                              hipStream_t stream) {
    const float* x     = (const float*)d_in[0];
    const float* W_in  = (const float*)d_in[1];
    const float* b_in  = (const float*)d_in[2];
    const float* W_hh  = (const float*)d_in[3];
    const float* b_hh  = (const float*)d_in[4];
    const float* W_out = (const float*)d_in[5];
    const float* b_out = (const float*)d_in[6];
    float* out = (float*)d_out;

    // workspace: [0,1MB) packed wb (512x512 dwords), [1MB,3MB) h (1024x512 f32)
    uint32* wb = (uint32*)d_ws;
    float*  h  = (float*)((char*)d_ws + (1u << 20));

    // 1) masked packed fp16-pair weights
    prep_kernel<<<dim3(1024), dim3(256), 0, stream>>>(W_hh, b_hh, wb);

    // 2) h0 = relu^2(x @ W_in + b_in)
    gemm_kernel<true><<<dim3(B_SZ / 64, HH / 32), dim3(256), 0, stream>>>(
        x, W_in, b_in, h, B_SZ, HH, DIN);

    // 3) blocked triangular scan, in-place on h
    scan_kernel<<<dim3(256), dim3(512), 0, stream>>>(wb, h);

    // 4) out = h @ W_out + b_out
    gemm_kernel<false><<<dim3(B_SZ / 64, DOUT / 32), dim3(256), 0, stream>>>(
        h, W_out, b_out, out, B_SZ, DOUT, HH);
}